// Round 9
// baseline (1087.978 us; speedup 1.0000x reference)
//
#include <hip/hip_runtime.h>
#include <math.h>

#define WD 64
#define TD 8192
#define NT 131072           // 16 * 8192 rows
#define KB 2048
// Output layout (float32, concatenated): x_l [NT], x_d [NT*WD], commit, fit, prenorm
#define OFF_XL 0
#define OFF_XD NT
#define OFF_SC (NT + NT * WD)

// ws layout (bytes)
#define RED_OFF   0                      // double[4]: xsum, xsumsq, fit, commit
#define CNT_OFF   32                     // uint: rescan count
#define KN2_OFF   4096                   // float[2048] np-exact ||k||^2
#define CB_OFF    16384                  // bf16 B-frags: 128jt * 4frag * 64lane * 16B = 512KB
#define M1_OFF    (16384 + 524288)       // float[NT]
#define M2_OFF    (M1_OFF + 4 * NT)      // float[NT]
#define J1_OFF    (M2_OFF + 4 * NT)      // int[NT]
#define LIST_OFF  (J1_OFF + 4 * NT)      // int[NT] rescan rows
#define P1_OFF    (LIST_OFF + 4 * NT)    // u64[NT] packed (dist_bits<<32)|idx per list pos
#define XR_OFF    (P1_OFF + 8 * NT)      // float[XRCAP][64] compacted rescan rows
#define XRCAP     32768                  // 8MB cap (expected count ~2.7k)

#define EPS_GAP 4e-3f    // approx top-2 gap below this -> exact rescan (~2% rows, r5/r7/r8)
#define VEPS    2e-3f    // |approx score(j1) - exact score(j1)| above this -> rescan (~0)

typedef __attribute__((ext_vector_type(8))) short bf16x8_t;  // 8 bf16 (4 VGPRs)
typedef __attribute__((ext_vector_type(4))) float f32x4_t;

__device__ __forceinline__ unsigned short bf16_rne(float f) {
  unsigned int u = __float_as_uint(f);
  unsigned int r = u + 0x7fffu + ((u >> 16) & 1u);
  return (unsigned short)(r >> 16);
}

#define REP64(F) F(0) F(1) F(2) F(3) F(4) F(5) F(6) F(7) \
  F(8) F(9) F(10) F(11) F(12) F(13) F(14) F(15) \
  F(16) F(17) F(18) F(19) F(20) F(21) F(22) F(23) \
  F(24) F(25) F(26) F(27) F(28) F(29) F(30) F(31) \
  F(32) F(33) F(34) F(35) F(36) F(37) F(38) F(39) \
  F(40) F(41) F(42) F(43) F(44) F(45) F(46) F(47) \
  F(48) F(49) F(50) F(51) F(52) F(53) F(54) F(55) \
  F(56) F(57) F(58) F(59) F(60) F(61) F(62) F(63)

// numpy pairwise_sum (scalar 8-accumulator, n=64) of PRE-ROUNDED squares; *_rn
// intrinsics forbid contraction. Bit-exact vs np.sum(a*a, -1) (verified r2-r8).
#define NP_SUMSQ64_NAMED(SVAR) \
  float r0 = __fmul_rn(x0, x0); \
  float r1 = __fmul_rn(x1, x1); \
  float r2 = __fmul_rn(x2, x2); \
  float r3 = __fmul_rn(x3, x3); \
  float r4 = __fmul_rn(x4, x4); \
  float r5 = __fmul_rn(x5, x5); \
  float r6 = __fmul_rn(x6, x6); \
  float r7 = __fmul_rn(x7, x7); \
  SQ8(8, 9, 10, 11, 12, 13, 14, 15) \
  SQ8(16, 17, 18, 19, 20, 21, 22, 23) \
  SQ8(24, 25, 26, 27, 28, 29, 30, 31) \
  SQ8(32, 33, 34, 35, 36, 37, 38, 39) \
  SQ8(40, 41, 42, 43, 44, 45, 46, 47) \
  SQ8(48, 49, 50, 51, 52, 53, 54, 55) \
  SQ8(56, 57, 58, 59, 60, 61, 62, 63) \
  const float SVAR = __fadd_rn(__fadd_rn(__fadd_rn(r0, r1), __fadd_rn(r2, r3)), \
                               __fadd_rn(__fadd_rn(r4, r5), __fadd_rn(r6, r7)));
#define SQ8(a,b,c,d,e,f,g,h) \
  r0 = __fadd_rn(r0, __fmul_rn(x##a, x##a)); \
  r1 = __fadd_rn(r1, __fmul_rn(x##b, x##b)); \
  r2 = __fadd_rn(r2, __fmul_rn(x##c, x##c)); \
  r3 = __fadd_rn(r3, __fmul_rn(x##d, x##d)); \
  r4 = __fadd_rn(r4, __fmul_rn(x##e, x##e)); \
  r5 = __fadd_rn(r5, __fmul_rn(x##f, x##f)); \
  r6 = __fadd_rn(r6, __fmul_rn(x##g, x##g)); \
  r7 = __fadd_rn(r7, __fmul_rn(x##h, x##h));

__device__ __forceinline__ float np_sumsq64_ptr(const float* a) {
  float r0 = __fmul_rn(a[0], a[0]);
  float r1 = __fmul_rn(a[1], a[1]);
  float r2 = __fmul_rn(a[2], a[2]);
  float r3 = __fmul_rn(a[3], a[3]);
  float r4 = __fmul_rn(a[4], a[4]);
  float r5 = __fmul_rn(a[5], a[5]);
  float r6 = __fmul_rn(a[6], a[6]);
  float r7 = __fmul_rn(a[7], a[7]);
#pragma unroll
  for (int i = 8; i < 64; i += 8) {
    r0 = __fadd_rn(r0, __fmul_rn(a[i + 0], a[i + 0]));
    r1 = __fadd_rn(r1, __fmul_rn(a[i + 1], a[i + 1]));
    r2 = __fadd_rn(r2, __fmul_rn(a[i + 2], a[i + 2]));
    r3 = __fadd_rn(r3, __fmul_rn(a[i + 3], a[i + 3]));
    r4 = __fadd_rn(r4, __fmul_rn(a[i + 4], a[i + 4]));
    r5 = __fadd_rn(r5, __fmul_rn(a[i + 5], a[i + 5]));
    r6 = __fadd_rn(r6, __fmul_rn(a[i + 6], a[i + 6]));
    r7 = __fadd_rn(r7, __fmul_rn(a[i + 7], a[i + 7]));
  }
  float t01 = __fadd_rn(r0, r1);
  float t23 = __fadd_rn(r2, r3);
  float t45 = __fadd_rn(r4, r5);
  float t67 = __fadd_rn(r6, r7);
  return __fadd_rn(__fadd_rn(t01, t23), __fadd_rn(t45, t67));
}

// ---------- K0: kn2_np + codebook bf16 hi/lo in B-fragment order ----------
__global__ __launch_bounds__(256)
void vq_prep(const float* __restrict__ k, char* __restrict__ wsb) {
  int c = blockIdx.x * 256 + threadIdx.x;
  if (c >= KB) return;
  const float* kr = k + (size_t)c * WD;
  ((float*)(wsb + KN2_OFF))[c] = np_sumsq64_ptr(kr);
  int jt = c >> 4, col = c & 15;
  unsigned short* cb = (unsigned short*)(wsb + CB_OFF);
#pragma unroll
  for (int w = 0; w < WD; ++w) {
    float f = kr[w];
    unsigned short hb = bf16_rne(f);
    float hf = __uint_as_float((unsigned int)hb << 16);
    unsigned short lb = bf16_rne(f - hf);
    int fH = w >> 5;                       // K-half: frag 0/1 (hi), 2/3 (lo)
    int lane = col | (((w >> 3) & 3) << 4);
    int e = w & 7;
    cb[((size_t)((jt * 4 + fH) * 64 + lane)) * 8 + e] = hb;
    cb[((size_t)((jt * 4 + 2 + fH) * 64 + lane)) * 8 + e] = lb;
  }
}

// ---------- K1: MFMA bf16x3 score scan -> per-row (m1, m2, j1) ----------
__global__ __launch_bounds__(256, 3)
void vq_scan(const float* __restrict__ x, char* __restrict__ wsb) {
  __shared__ float lkn2[KB];
  for (int i = threadIdx.x; i < KB; i += 256)
    lkn2[i] = ((const float*)(wsb + KN2_OFF))[i];
  __syncthreads();

  const int tid = threadIdx.x, lane = tid & 63, wave = tid >> 6;
  const int col = lane & 15, grp = lane >> 4;
  const int n = blockIdx.x >> 6;           // 64 blocks per n (8192/128)
  const int t0 = (blockIdx.x & 63) * 128;
  const float* xb = x + (size_t)n * WD * TD;

  bf16x8_t aH[2][2], aL[2][2];             // [tile][k-step]
#pragma unroll
  for (int T = 0; T < 2; ++T) {
    int trow = t0 + wave * 32 + T * 16 + col;
#pragma unroll
    for (int s = 0; s < 2; ++s) {
#pragma unroll
      for (int e = 0; e < 8; ++e) {
        int w = s * 32 + grp * 8 + e;
        float f = xb[(size_t)w * TD + trow];
        unsigned short hb = bf16_rne(f);
        float hf = __uint_as_float((unsigned int)hb << 16);
        unsigned short lb = bf16_rne(f - hf);
        aH[T][s][e] = (short)hb;
        aL[T][s][e] = (short)lb;
      }
    }
  }

  float m1v[2][4], m2v[2][4];
  int j1v[2][4];
#pragma unroll
  for (int T = 0; T < 2; ++T)
#pragma unroll
    for (int e = 0; e < 4; ++e) {
      m1v[T][e] = INFINITY; m2v[T][e] = INFINITY; j1v[T][e] = 0;
    }

  const bf16x8_t* cb = (const bf16x8_t*)(wsb + CB_OFF);
  const f32x4_t zero4 = {0.f, 0.f, 0.f, 0.f};

  for (int jt = 0; jt < 128; ++jt) {
    const bf16x8_t* bp = cb + (size_t)jt * 256 + lane;
    bf16x8_t bH0 = bp[0], bH1 = bp[64], bL0 = bp[128], bL1 = bp[192];
    float kv = lkn2[jt * 16 + col];
    f32x4_t aA0 = __builtin_amdgcn_mfma_f32_16x16x32_bf16(aH[0][0], bH0, zero4, 0, 0, 0);
    f32x4_t aB0 = __builtin_amdgcn_mfma_f32_16x16x32_bf16(aH[0][1], bH1, zero4, 0, 0, 0);
    f32x4_t aA1 = __builtin_amdgcn_mfma_f32_16x16x32_bf16(aH[1][0], bH0, zero4, 0, 0, 0);
    f32x4_t aB1 = __builtin_amdgcn_mfma_f32_16x16x32_bf16(aH[1][1], bH1, zero4, 0, 0, 0);
    aA0 = __builtin_amdgcn_mfma_f32_16x16x32_bf16(aL[0][0], bH0, aA0, 0, 0, 0);
    aB0 = __builtin_amdgcn_mfma_f32_16x16x32_bf16(aL[0][1], bH1, aB0, 0, 0, 0);
    aA1 = __builtin_amdgcn_mfma_f32_16x16x32_bf16(aL[1][0], bH0, aA1, 0, 0, 0);
    aB1 = __builtin_amdgcn_mfma_f32_16x16x32_bf16(aL[1][1], bH1, aB1, 0, 0, 0);
    aA0 = __builtin_amdgcn_mfma_f32_16x16x32_bf16(aH[0][0], bL0, aA0, 0, 0, 0);
    aB0 = __builtin_amdgcn_mfma_f32_16x16x32_bf16(aH[0][1], bL1, aB0, 0, 0, 0);
    aA1 = __builtin_amdgcn_mfma_f32_16x16x32_bf16(aH[1][0], bL0, aA1, 0, 0, 0);
    aB1 = __builtin_amdgcn_mfma_f32_16x16x32_bf16(aH[1][1], bL1, aB1, 0, 0, 0);

    int cd = jt * 16 + col;
#define UPD(T, E, V) { bool b = (V) < m1v[T][E]; \
      m2v[T][E] = b ? m1v[T][E] : fminf(m2v[T][E], (V)); \
      m1v[T][E] = b ? (V) : m1v[T][E]; \
      j1v[T][E] = b ? cd : j1v[T][E]; }
    {
      float v0 = fmaf(-2.f, aA0[0] + aB0[0], kv);
      float v1 = fmaf(-2.f, aA0[1] + aB0[1], kv);
      float v2 = fmaf(-2.f, aA0[2] + aB0[2], kv);
      float v3 = fmaf(-2.f, aA0[3] + aB0[3], kv);
      UPD(0, 0, v0) UPD(0, 1, v1) UPD(0, 2, v2) UPD(0, 3, v3)
      float u0 = fmaf(-2.f, aA1[0] + aB1[0], kv);
      float u1 = fmaf(-2.f, aA1[1] + aB1[1], kv);
      float u2 = fmaf(-2.f, aA1[2] + aB1[2], kv);
      float u3 = fmaf(-2.f, aA1[3] + aB1[3], kv);
      UPD(1, 0, u0) UPD(1, 1, u1) UPD(1, 2, u2) UPD(1, 3, u3)
    }
#undef UPD
  }

#pragma unroll
  for (int T = 0; T < 2; ++T)
#pragma unroll
    for (int e = 0; e < 4; ++e) {
      float m1 = m1v[T][e], m2 = m2v[T][e];
      int j1 = j1v[T][e];
#pragma unroll
      for (int d = 1; d < 16; d <<= 1) {
        float om1 = __shfl_xor(m1, d, 64);
        float om2 = __shfl_xor(m2, d, 64);
        int oj = __shfl_xor(j1, d, 64);
        bool take = (om1 < m1) || (om1 == m1 && oj < j1);
        float loser = take ? m1 : om1;
        m2 = fminf(fminf(m2, om2), loser);
        m1 = take ? om1 : m1;
        j1 = take ? oj : j1;
      }
      if (col == 0) {
        int row = blockIdx.x * 128 + wave * 32 + T * 16 + grp * 4 + e;
        ((float*)(wsb + M1_OFF))[row] = m1;
        ((float*)(wsb + M2_OFF))[row] = m2;
        ((int*)(wsb + J1_OFF))[row] = j1;
      }
    }
}

// ---------- K2: per-row finalize: verify j1, epilogue, flag + compact rescans ----------
__global__ __launch_bounds__(256, 4)
void vq_fin(const float* __restrict__ x, const float* __restrict__ k,
            float* __restrict__ out, char* __restrict__ wsb) {
  __shared__ double sred[16];
  const int tid = threadIdx.x;
  const int row = blockIdx.x * 256 + tid;
  const int n = row >> 13;
  const int t = row & (TD - 1);

  float m1r = ((const float*)(wsb + M1_OFF))[row];
  float m2r = ((const float*)(wsb + M2_OFF))[row];
  int j1r = ((const int*)(wsb + J1_OFF))[row];

  const float* xr = x + ((size_t)n * WD) * TD + t;
#define LOADX(w) float x##w = xr[(size_t)(w) * TD];
  REP64(LOADX)
#undef LOADX

  NP_SUMSQ64_NAMED(s)

  double xsum = 0.0, xsumsq = 0.0;
#define PRE(w) { double xd = (double)x##w; xsum += xd; xsumsq = fma(xd, xd, xsumsq); }
  REP64(PRE)
#undef PRE

  const float* kbr = k + (size_t)j1r * WD;
  float* xo = out + OFF_XD + ((size_t)n * WD) * TD + t;
  double commit = 0.0;
  float g = 0.f;
#define EPI(w) { \
    float kw = kbr[w]; \
    float diff = __fsub_rn(kw, x##w); \
    commit = fma((double)diff, (double)diff, commit); \
    g = __fmaf_rn(x##w, kw, g); \
    xo[(size_t)(w) * TD] = __fadd_rn(x##w, diff); }
  REP64(EPI)
#undef EPI

  float kn2j = ((const float*)(wsb + KN2_OFF))[j1r];
  float score = kn2j - 2.f * g;
  bool resc = (m2r - m1r < EPS_GAP) || (fabsf(score - m1r) > VEPS);
  float dist1 = __fadd_rn(__fsub_rn(s, __fmul_rn(2.f, g)), kn2j);

  out[OFF_XL + row] = (float)j1r;
  if (resc) {
    unsigned idx = atomicAdd((unsigned*)(wsb + CNT_OFF), 1u);
    ((int*)(wsb + LIST_OFF))[idx] = row;
    ((unsigned long long*)(wsb + P1_OFF))[idx] = ~0ull;   // init packed min slot
    if (idx < XRCAP) {                                    // compact row for rescan
      float* xrw = (float*)(wsb + XR_OFF) + (size_t)idx * WD;
#define XWR(w) xrw[w] = x##w;
      REP64(XWR)
#undef XWR
    }
  }

  double v0 = xsum, v1 = xsumsq;
  double v2 = resc ? 0.0 : (double)dist1;
  double v3 = resc ? 0.0 : commit;
#pragma unroll
  for (int off = 32; off > 0; off >>= 1) {
    v0 += __shfl_down(v0, off, 64);
    v1 += __shfl_down(v1, off, 64);
    v2 += __shfl_down(v2, off, 64);
    v3 += __shfl_down(v3, off, 64);
  }
  if ((tid & 63) == 0) {
    int wv = tid >> 6;
    sred[wv * 4 + 0] = v0;
    sred[wv * 4 + 1] = v1;
    sred[wv * 4 + 2] = v2;
    sred[wv * 4 + 3] = v3;
  }
  __syncthreads();
  if (tid == 0) {
    double a0 = 0, a1 = 0, a2 = 0, a3 = 0;
#pragma unroll
    for (int w2 = 0; w2 < 4; ++w2) {
      a0 += sred[w2 * 4 + 0];
      a1 += sred[w2 * 4 + 1];
      a2 += sred[w2 * 4 + 2];
      a3 += sred[w2 * 4 + 3];
    }
    double* red = (double*)(wsb + RED_OFF);
    atomicAdd(&red[0], a0);
    atomicAdd(&red[1], a1);
    atomicAdd(&red[2], a2);
    atomicAdd(&red[3], a3);
  }
}

// ---------- K3: exact rescan, LDS-staged codebook chunk ----------
// Block = (chunk of 128 codes, row-group). Stage chunk (32KB) to LDS once;
// each thread = one listed row (x from compacted XR, coalesced), scans the
// chunk with np-exact 4-chain FMAs (broadcast ds_reads). Packed u64 atomicMin
// across chunks == numpy first-index argmin (dist > 0 -> bit order == order).
__global__ __launch_bounds__(256) __attribute__((amdgpu_waves_per_eu(2, 2)))
void vq_rescan3(const float* __restrict__ x, const float* __restrict__ k,
                char* __restrict__ wsb) {
  __shared__ float klds[128 * WD];   // 32KB
  const unsigned count = *(const unsigned*)(wsb + CNT_OFF);
  const int tid = threadIdx.x;
  const int chunk = blockIdx.x & 15;
  const unsigned rgrp = blockIdx.x >> 4;
  const int cbase = chunk * 128;

  {  // stage chunk: 256 threads x 8 float4, coalesced
    const float4* ksrc = (const float4*)(k + (size_t)cbase * WD);
    float4* kdst = (float4*)klds;
#pragma unroll
    for (int j = 0; j < 8; ++j) kdst[tid + 256 * j] = ksrc[tid + 256 * j];
  }
  __syncthreads();

  const int* list = (const int*)(wsb + LIST_OFF);
  unsigned long long* P1 = (unsigned long long*)(wsb + P1_OFF);
  const float* kn2 = (const float*)(wsb + KN2_OFF);
  const float* XR = (const float*)(wsb + XR_OFF);

  for (unsigned base = rgrp * 256u; base < count; base += 4096u) {
    const unsigned li = base + (unsigned)tid;
    if (li >= count) continue;                // no barriers below: safe

    float x0, x1, x2, x3, x4, x5, x6, x7, x8, x9, x10, x11, x12, x13, x14, x15,
        x16, x17, x18, x19, x20, x21, x22, x23, x24, x25, x26, x27, x28, x29,
        x30, x31, x32, x33, x34, x35, x36, x37, x38, x39, x40, x41, x42, x43,
        x44, x45, x46, x47, x48, x49, x50, x51, x52, x53, x54, x55, x56, x57,
        x58, x59, x60, x61, x62, x63;
    if (li < XRCAP) {
      const float* xr = XR + (size_t)li * WD;   // contiguous 256B, coalesced
#define LX(w) x##w = xr[w];
      REP64(LX)
#undef LX
    } else {                                    // fallback: strided from x
      const int row = list[li];
      const int n = row >> 13, t = row & (TD - 1);
      const float* xr = x + (size_t)n * WD * TD + t;
#define LX(w) x##w = xr[(size_t)(w) * TD];
      REP64(LX)
#undef LX
    }

    NP_SUMSQ64_NAMED(s)

    unsigned long long best = ~0ull;
    for (int it = 0; it < 32; ++it) {
      const int c = it * 4;
      const float* k0p = klds + (size_t)c * WD;
      const float* k1p = k0p + WD;
      const float* k2p = k0p + 2 * WD;
      const float* k3p = k0p + 3 * WD;
      float g0 = 0.f, g1 = 0.f, g2 = 0.f, g3 = 0.f;
#define FMA4(w) \
      g0 = __fmaf_rn(x##w, k0p[w], g0); \
      g1 = __fmaf_rn(x##w, k1p[w], g1); \
      g2 = __fmaf_rn(x##w, k2p[w], g2); \
      g3 = __fmaf_rn(x##w, k3p[w], g3);
      REP64(FMA4)
#undef FMA4
      const int cg = cbase + c;
      float d0 = __fadd_rn(__fsub_rn(s, __fmul_rn(2.0f, g0)), kn2[cg]);
      float d1 = __fadd_rn(__fsub_rn(s, __fmul_rn(2.0f, g1)), kn2[cg + 1]);
      float d2 = __fadd_rn(__fsub_rn(s, __fmul_rn(2.0f, g2)), kn2[cg + 2]);
      float d3 = __fadd_rn(__fsub_rn(s, __fmul_rn(2.0f, g3)), kn2[cg + 3]);
      unsigned long long p0 = ((unsigned long long)__float_as_uint(d0) << 32) | (unsigned)(cg);
      unsigned long long p1 = ((unsigned long long)__float_as_uint(d1) << 32) | (unsigned)(cg + 1);
      unsigned long long p2 = ((unsigned long long)__float_as_uint(d2) << 32) | (unsigned)(cg + 2);
      unsigned long long p3 = ((unsigned long long)__float_as_uint(d3) << 32) | (unsigned)(cg + 3);
      best = p0 < best ? p0 : best;
      best = p1 < best ? p1 : best;
      best = p2 < best ? p2 : best;
      best = p3 < best ? p3 : best;
    }
    atomicMin(&P1[li], best);
  }
}

// ---------- K4: apply rescan result: one wave per listed row ----------
__global__ __launch_bounds__(64)
void vq_rescan_fix(const float* __restrict__ x, const float* __restrict__ k,
                   float* __restrict__ out, char* __restrict__ wsb) {
  const unsigned count = *(const unsigned*)(wsb + CNT_OFF);
  const int* list = (const int*)(wsb + LIST_OFF);
  const unsigned long long* P1 = (const unsigned long long*)(wsb + P1_OFF);
  const float* XR = (const float*)(wsb + XR_OFF);
  double* red = (double*)(wsb + RED_OFF);
  const int lane = threadIdx.x;

  for (unsigned i = blockIdx.x; i < count; i += gridDim.x) {
    const int row = list[i];
    const unsigned long long best = P1[i];
    const int bi = (int)(best & 0xffffffffu);
    const float bv = __uint_as_float((unsigned)(best >> 32));
    const int n = row >> 13, t = row & (TD - 1);
    float xw = (i < XRCAP) ? XR[(size_t)i * WD + lane]
                           : x[(size_t)n * WD * TD + (size_t)lane * TD + t];
    float kw = k[(size_t)bi * WD + lane];
    float diff = __fsub_rn(kw, xw);
    out[OFF_XD + (size_t)n * WD * TD + (size_t)lane * TD + t] = __fadd_rn(xw, diff);
    double d2 = (double)diff * (double)diff;
#pragma unroll
    for (int dd = 32; dd > 0; dd >>= 1) d2 += __shfl_down(d2, dd, 64);
    if (lane == 0) {
      out[OFF_XL + row] = (float)bi;
      atomicAdd(&red[2], (double)bv);
      atomicAdd(&red[3], d2);
    }
  }
}

__global__ void vq_final(const char* __restrict__ wsb, float* __restrict__ out) {
  const double* red = (const double*)(wsb + RED_OFF);
  double sum = red[0], sumsq = red[1];
  double mean = sum / 8388608.0;
  double ss = sumsq - sum * mean;
  if (ss < 0.0) ss = 0.0;
  out[OFF_SC + 0] = (float)(red[3] / 8388608.0);       // commit_loss
  out[OFF_SC + 1] = (float)(red[2] / 131072.0);        // fit
  out[OFF_SC + 2] = (float)sqrt(ss / 8388608.0);       // prenorm
}

extern "C" void kernel_launch(void* const* d_in, const int* in_sizes, int n_in,
                              void* d_out, int out_size, void* d_ws, size_t ws_size,
                              hipStream_t stream) {
  const float* x = (const float*)d_in[0];
  const float* k = (const float*)d_in[1];
  float* out = (float*)d_out;
  char* wsb = (char*)d_ws;

  hipMemsetAsync(d_ws, 0, 64, stream);                 // red[4] + count
  vq_prep<<<KB / 256, 256, 0, stream>>>(k, wsb);
  vq_scan<<<NT / 128, 256, 0, stream>>>(x, wsb);
  vq_fin<<<NT / 256, 256, 0, stream>>>(x, k, out, wsb);
  vq_rescan3<<<256, 256, 0, stream>>>(x, k, wsb);
  vq_rescan_fix<<<1024, 64, 0, stream>>>(x, k, out, wsb);
  vq_final<<<1, 1, 0, stream>>>(wsb, out);
}

// Round 10
// 698.307 us; speedup vs baseline: 1.5580x; 1.5580x over previous
//
#include <hip/hip_runtime.h>
#include <math.h>

#define WD 64
#define TD 8192
#define NT 131072           // 16 * 8192 rows
#define KB 2048
// Output layout (float32, concatenated): x_l [NT], x_d [NT*WD], commit, fit, prenorm
#define OFF_XL 0
#define OFF_XD NT
#define OFF_SC (NT + NT * WD)

// ws layout (bytes)
#define RED_OFF   0                      // double[4]: xsum, xsumsq, fit, commit
#define CNT_OFF   32                     // uint: rescan count
#define KN2_OFF   4096                   // float[2048] np-exact ||k||^2
#define CB_OFF    16384                  // bf16 B-frags: 128jt * 4frag * 64lane * 16B = 512KB
#define M1_OFF    (16384 + 524288)       // float[NT]
#define M2_OFF    (M1_OFF + 4 * NT)      // float[NT]
#define J1_OFF    (M2_OFF + 4 * NT)      // int[NT]
#define LIST_OFF  (J1_OFF + 4 * NT)      // int[NT] rescan rows
#define P1_OFF    (LIST_OFF + 4 * NT)    // (unused this round; kept for layout stability)
#define XR_OFF    (P1_OFF + 8 * NT)      // float[XRCAP][64] compacted rescan rows
#define XRCAP     32768                  // 8MB cap (expected count ~2.7k; r9 confirmed in-cap)

#define EPS_GAP 4e-3f    // approx top-2 gap below this -> exact rescan (~2% rows)
#define VEPS    2e-3f    // |approx score(j1) - exact score(j1)| above this -> rescan (~0)

typedef __attribute__((ext_vector_type(8))) short bf16x8_t;  // 8 bf16 (4 VGPRs)
typedef __attribute__((ext_vector_type(4))) float f32x4_t;

__device__ __forceinline__ unsigned short bf16_rne(float f) {
  unsigned int u = __float_as_uint(f);
  unsigned int r = u + 0x7fffu + ((u >> 16) & 1u);
  return (unsigned short)(r >> 16);
}

#define REP64(F) F(0) F(1) F(2) F(3) F(4) F(5) F(6) F(7) \
  F(8) F(9) F(10) F(11) F(12) F(13) F(14) F(15) \
  F(16) F(17) F(18) F(19) F(20) F(21) F(22) F(23) \
  F(24) F(25) F(26) F(27) F(28) F(29) F(30) F(31) \
  F(32) F(33) F(34) F(35) F(36) F(37) F(38) F(39) \
  F(40) F(41) F(42) F(43) F(44) F(45) F(46) F(47) \
  F(48) F(49) F(50) F(51) F(52) F(53) F(54) F(55) \
  F(56) F(57) F(58) F(59) F(60) F(61) F(62) F(63)

// numpy pairwise_sum (scalar 8-accumulator, n=64) of PRE-ROUNDED squares; *_rn
// intrinsics forbid contraction. Bit-exact vs np.sum(a*a, -1) (verified r2-r9).
#define NP_SUMSQ64_NAMED(SVAR) \
  float r0 = __fmul_rn(x0, x0); \
  float r1 = __fmul_rn(x1, x1); \
  float r2 = __fmul_rn(x2, x2); \
  float r3 = __fmul_rn(x3, x3); \
  float r4 = __fmul_rn(x4, x4); \
  float r5 = __fmul_rn(x5, x5); \
  float r6 = __fmul_rn(x6, x6); \
  float r7 = __fmul_rn(x7, x7); \
  SQ8(8, 9, 10, 11, 12, 13, 14, 15) \
  SQ8(16, 17, 18, 19, 20, 21, 22, 23) \
  SQ8(24, 25, 26, 27, 28, 29, 30, 31) \
  SQ8(32, 33, 34, 35, 36, 37, 38, 39) \
  SQ8(40, 41, 42, 43, 44, 45, 46, 47) \
  SQ8(48, 49, 50, 51, 52, 53, 54, 55) \
  SQ8(56, 57, 58, 59, 60, 61, 62, 63) \
  const float SVAR = __fadd_rn(__fadd_rn(__fadd_rn(r0, r1), __fadd_rn(r2, r3)), \
                               __fadd_rn(__fadd_rn(r4, r5), __fadd_rn(r6, r7)));
#define SQ8(a,b,c,d,e,f,g,h) \
  r0 = __fadd_rn(r0, __fmul_rn(x##a, x##a)); \
  r1 = __fadd_rn(r1, __fmul_rn(x##b, x##b)); \
  r2 = __fadd_rn(r2, __fmul_rn(x##c, x##c)); \
  r3 = __fadd_rn(r3, __fmul_rn(x##d, x##d)); \
  r4 = __fadd_rn(r4, __fmul_rn(x##e, x##e)); \
  r5 = __fadd_rn(r5, __fmul_rn(x##f, x##f)); \
  r6 = __fadd_rn(r6, __fmul_rn(x##g, x##g)); \
  r7 = __fadd_rn(r7, __fmul_rn(x##h, x##h));

__device__ __forceinline__ float np_sumsq64_ptr(const float* a) {
  float r0 = __fmul_rn(a[0], a[0]);
  float r1 = __fmul_rn(a[1], a[1]);
  float r2 = __fmul_rn(a[2], a[2]);
  float r3 = __fmul_rn(a[3], a[3]);
  float r4 = __fmul_rn(a[4], a[4]);
  float r5 = __fmul_rn(a[5], a[5]);
  float r6 = __fmul_rn(a[6], a[6]);
  float r7 = __fmul_rn(a[7], a[7]);
#pragma unroll
  for (int i = 8; i < 64; i += 8) {
    r0 = __fadd_rn(r0, __fmul_rn(a[i + 0], a[i + 0]));
    r1 = __fadd_rn(r1, __fmul_rn(a[i + 1], a[i + 1]));
    r2 = __fadd_rn(r2, __fmul_rn(a[i + 2], a[i + 2]));
    r3 = __fadd_rn(r3, __fmul_rn(a[i + 3], a[i + 3]));
    r4 = __fadd_rn(r4, __fmul_rn(a[i + 4], a[i + 4]));
    r5 = __fadd_rn(r5, __fmul_rn(a[i + 5], a[i + 5]));
    r6 = __fadd_rn(r6, __fmul_rn(a[i + 6], a[i + 6]));
    r7 = __fadd_rn(r7, __fmul_rn(a[i + 7], a[i + 7]));
  }
  float t01 = __fadd_rn(r0, r1);
  float t23 = __fadd_rn(r2, r3);
  float t45 = __fadd_rn(r4, r5);
  float t67 = __fadd_rn(r6, r7);
  return __fadd_rn(__fadd_rn(t01, t23), __fadd_rn(t45, t67));
}

// ---------- K0: kn2_np + codebook bf16 hi/lo in B-fragment order ----------
__global__ __launch_bounds__(256)
void vq_prep(const float* __restrict__ k, char* __restrict__ wsb) {
  int c = blockIdx.x * 256 + threadIdx.x;
  if (c >= KB) return;
  const float* kr = k + (size_t)c * WD;
  ((float*)(wsb + KN2_OFF))[c] = np_sumsq64_ptr(kr);
  int jt = c >> 4, col = c & 15;
  unsigned short* cb = (unsigned short*)(wsb + CB_OFF);
#pragma unroll
  for (int w = 0; w < WD; ++w) {
    float f = kr[w];
    unsigned short hb = bf16_rne(f);
    float hf = __uint_as_float((unsigned int)hb << 16);
    unsigned short lb = bf16_rne(f - hf);
    int fH = w >> 5;                       // K-half: frag 0/1 (hi), 2/3 (lo)
    int lane = col | (((w >> 3) & 3) << 4);
    int e = w & 7;
    cb[((size_t)((jt * 4 + fH) * 64 + lane)) * 8 + e] = hb;
    cb[((size_t)((jt * 4 + 2 + fH) * 64 + lane)) * 8 + e] = lb;
  }
}

// ---------- K1: MFMA bf16x3 score scan -> per-row (m1, m2, j1) ----------
__global__ __launch_bounds__(256, 3)
void vq_scan(const float* __restrict__ x, char* __restrict__ wsb) {
  __shared__ float lkn2[KB];
  for (int i = threadIdx.x; i < KB; i += 256)
    lkn2[i] = ((const float*)(wsb + KN2_OFF))[i];
  __syncthreads();

  const int tid = threadIdx.x, lane = tid & 63, wave = tid >> 6;
  const int col = lane & 15, grp = lane >> 4;
  const int n = blockIdx.x >> 6;           // 64 blocks per n (8192/128)
  const int t0 = (blockIdx.x & 63) * 128;
  const float* xb = x + (size_t)n * WD * TD;

  bf16x8_t aH[2][2], aL[2][2];             // [tile][k-step]
#pragma unroll
  for (int T = 0; T < 2; ++T) {
    int trow = t0 + wave * 32 + T * 16 + col;
#pragma unroll
    for (int s = 0; s < 2; ++s) {
#pragma unroll
      for (int e = 0; e < 8; ++e) {
        int w = s * 32 + grp * 8 + e;
        float f = xb[(size_t)w * TD + trow];
        unsigned short hb = bf16_rne(f);
        float hf = __uint_as_float((unsigned int)hb << 16);
        unsigned short lb = bf16_rne(f - hf);
        aH[T][s][e] = (short)hb;
        aL[T][s][e] = (short)lb;
      }
    }
  }

  float m1v[2][4], m2v[2][4];
  int j1v[2][4];
#pragma unroll
  for (int T = 0; T < 2; ++T)
#pragma unroll
    for (int e = 0; e < 4; ++e) {
      m1v[T][e] = INFINITY; m2v[T][e] = INFINITY; j1v[T][e] = 0;
    }

  const bf16x8_t* cb = (const bf16x8_t*)(wsb + CB_OFF);
  const f32x4_t zero4 = {0.f, 0.f, 0.f, 0.f};

  for (int jt = 0; jt < 128; ++jt) {
    const bf16x8_t* bp = cb + (size_t)jt * 256 + lane;
    bf16x8_t bH0 = bp[0], bH1 = bp[64], bL0 = bp[128], bL1 = bp[192];
    float kv = lkn2[jt * 16 + col];
    f32x4_t aA0 = __builtin_amdgcn_mfma_f32_16x16x32_bf16(aH[0][0], bH0, zero4, 0, 0, 0);
    f32x4_t aB0 = __builtin_amdgcn_mfma_f32_16x16x32_bf16(aH[0][1], bH1, zero4, 0, 0, 0);
    f32x4_t aA1 = __builtin_amdgcn_mfma_f32_16x16x32_bf16(aH[1][0], bH0, zero4, 0, 0, 0);
    f32x4_t aB1 = __builtin_amdgcn_mfma_f32_16x16x32_bf16(aH[1][1], bH1, zero4, 0, 0, 0);
    aA0 = __builtin_amdgcn_mfma_f32_16x16x32_bf16(aL[0][0], bH0, aA0, 0, 0, 0);
    aB0 = __builtin_amdgcn_mfma_f32_16x16x32_bf16(aL[0][1], bH1, aB0, 0, 0, 0);
    aA1 = __builtin_amdgcn_mfma_f32_16x16x32_bf16(aL[1][0], bH0, aA1, 0, 0, 0);
    aB1 = __builtin_amdgcn_mfma_f32_16x16x32_bf16(aL[1][1], bH1, aB1, 0, 0, 0);
    aA0 = __builtin_amdgcn_mfma_f32_16x16x32_bf16(aH[0][0], bL0, aA0, 0, 0, 0);
    aB0 = __builtin_amdgcn_mfma_f32_16x16x32_bf16(aH[0][1], bL1, aB0, 0, 0, 0);
    aA1 = __builtin_amdgcn_mfma_f32_16x16x32_bf16(aH[1][0], bL0, aA1, 0, 0, 0);
    aB1 = __builtin_amdgcn_mfma_f32_16x16x32_bf16(aH[1][1], bL1, aB1, 0, 0, 0);

    int cd = jt * 16 + col;
#define UPD(T, E, V) { bool b = (V) < m1v[T][E]; \
      m2v[T][E] = b ? m1v[T][E] : fminf(m2v[T][E], (V)); \
      m1v[T][E] = b ? (V) : m1v[T][E]; \
      j1v[T][E] = b ? cd : j1v[T][E]; }
    {
      float v0 = fmaf(-2.f, aA0[0] + aB0[0], kv);
      float v1 = fmaf(-2.f, aA0[1] + aB0[1], kv);
      float v2 = fmaf(-2.f, aA0[2] + aB0[2], kv);
      float v3 = fmaf(-2.f, aA0[3] + aB0[3], kv);
      UPD(0, 0, v0) UPD(0, 1, v1) UPD(0, 2, v2) UPD(0, 3, v3)
      float u0 = fmaf(-2.f, aA1[0] + aB1[0], kv);
      float u1 = fmaf(-2.f, aA1[1] + aB1[1], kv);
      float u2 = fmaf(-2.f, aA1[2] + aB1[2], kv);
      float u3 = fmaf(-2.f, aA1[3] + aB1[3], kv);
      UPD(1, 0, u0) UPD(1, 1, u1) UPD(1, 2, u2) UPD(1, 3, u3)
    }
#undef UPD
  }

#pragma unroll
  for (int T = 0; T < 2; ++T)
#pragma unroll
    for (int e = 0; e < 4; ++e) {
      float m1 = m1v[T][e], m2 = m2v[T][e];
      int j1 = j1v[T][e];
#pragma unroll
      for (int d = 1; d < 16; d <<= 1) {
        float om1 = __shfl_xor(m1, d, 64);
        float om2 = __shfl_xor(m2, d, 64);
        int oj = __shfl_xor(j1, d, 64);
        bool take = (om1 < m1) || (om1 == m1 && oj < j1);
        float loser = take ? m1 : om1;
        m2 = fminf(fminf(m2, om2), loser);
        m1 = take ? om1 : m1;
        j1 = take ? oj : j1;
      }
      if (col == 0) {
        int row = blockIdx.x * 128 + wave * 32 + T * 16 + grp * 4 + e;
        ((float*)(wsb + M1_OFF))[row] = m1;
        ((float*)(wsb + M2_OFF))[row] = m2;
        ((int*)(wsb + J1_OFF))[row] = j1;
      }
    }
}

// ---------- K2: per-row finalize: verify j1, epilogue, flag + compact rescans ----------
__global__ __launch_bounds__(256, 4)
void vq_fin(const float* __restrict__ x, const float* __restrict__ k,
            float* __restrict__ out, char* __restrict__ wsb) {
  __shared__ double sred[16];
  const int tid = threadIdx.x;
  const int row = blockIdx.x * 256 + tid;
  const int n = row >> 13;
  const int t = row & (TD - 1);

  float m1r = ((const float*)(wsb + M1_OFF))[row];
  float m2r = ((const float*)(wsb + M2_OFF))[row];
  int j1r = ((const int*)(wsb + J1_OFF))[row];

  const float* xr = x + ((size_t)n * WD) * TD + t;
#define LOADX(w) float x##w = xr[(size_t)(w) * TD];
  REP64(LOADX)
#undef LOADX

  NP_SUMSQ64_NAMED(s)

  double xsum = 0.0, xsumsq = 0.0;
#define PRE(w) { double xd = (double)x##w; xsum += xd; xsumsq = fma(xd, xd, xsumsq); }
  REP64(PRE)
#undef PRE

  const float* kbr = k + (size_t)j1r * WD;
  float* xo = out + OFF_XD + ((size_t)n * WD) * TD + t;
  double commit = 0.0;
  float g = 0.f;
#define EPI(w) { \
    float kw = kbr[w]; \
    float diff = __fsub_rn(kw, x##w); \
    commit = fma((double)diff, (double)diff, commit); \
    g = __fmaf_rn(x##w, kw, g); \
    xo[(size_t)(w) * TD] = __fadd_rn(x##w, diff); }
  REP64(EPI)
#undef EPI

  float kn2j = ((const float*)(wsb + KN2_OFF))[j1r];
  float score = kn2j - 2.f * g;
  bool resc = (m2r - m1r < EPS_GAP) || (fabsf(score - m1r) > VEPS);
  float dist1 = __fadd_rn(__fsub_rn(s, __fmul_rn(2.f, g)), kn2j);

  out[OFF_XL + row] = (float)j1r;
  if (resc) {
    unsigned idx = atomicAdd((unsigned*)(wsb + CNT_OFF), 1u);
    ((int*)(wsb + LIST_OFF))[idx] = row;
    if (idx < XRCAP) {                                    // compact row for rescan
      float* xrw = (float*)(wsb + XR_OFF) + (size_t)idx * WD;
#define XWR(w) xrw[w] = x##w;
      REP64(XWR)
#undef XWR
    }
  }

  double v0 = xsum, v1 = xsumsq;
  double v2 = resc ? 0.0 : (double)dist1;
  double v3 = resc ? 0.0 : commit;
#pragma unroll
  for (int off = 32; off > 0; off >>= 1) {
    v0 += __shfl_down(v0, off, 64);
    v1 += __shfl_down(v1, off, 64);
    v2 += __shfl_down(v2, off, 64);
    v3 += __shfl_down(v3, off, 64);
  }
  if ((tid & 63) == 0) {
    int wv = tid >> 6;
    sred[wv * 4 + 0] = v0;
    sred[wv * 4 + 1] = v1;
    sred[wv * 4 + 2] = v2;
    sred[wv * 4 + 3] = v3;
  }
  __syncthreads();
  if (tid == 0) {
    double a0 = 0, a1 = 0, a2 = 0, a3 = 0;
#pragma unroll
    for (int w2 = 0; w2 < 4; ++w2) {
      a0 += sred[w2 * 4 + 0];
      a1 += sred[w2 * 4 + 1];
      a2 += sred[w2 * 4 + 2];
      a3 += sred[w2 * 4 + 3];
    }
    double* red = (double*)(wsb + RED_OFF);
    atomicAdd(&red[0], a0);
    atomicAdd(&red[1], a1);
    atomicAdd(&red[2], a2);
    atomicAdd(&red[3], a3);
  }
}

// ---------- K3: exact rescan, one block per listed row ----------
// x row in LDS (256B), NOT per-thread registers (r9 lesson: 64 named floats in
// a loop body spilled -> 215MB scratch traffic). 256 threads x 8 codes each,
// 2x4-code ILP groups; k via per-thread float4 streams (L2-resident 512KB);
// xs[w] reads are wave-uniform LDS broadcasts. np-exact *_rn chain per code.
// Block-level packed-u64 argmin (first-index on ties), epilogue folded in.
__global__ __launch_bounds__(256)
void vq_rescan4(const float* __restrict__ x, const float* __restrict__ k,
                float* __restrict__ out, char* __restrict__ wsb) {
  __shared__ float xs[WD];
  __shared__ unsigned long long wred[4];
  __shared__ unsigned long long bbest;
  const unsigned count = *(const unsigned*)(wsb + CNT_OFF);
  const int* list = (const int*)(wsb + LIST_OFF);
  const float* kn2 = (const float*)(wsb + KN2_OFF);
  const float* XR = (const float*)(wsb + XR_OFF);
  double* red = (double*)(wsb + RED_OFF);
  const int tid = threadIdx.x;
  const int lane = tid & 63, wv = tid >> 6;

  for (unsigned li = blockIdx.x; li < count; li += gridDim.x) {
    const int row = list[li];
    const int n = row >> 13, t = row & (TD - 1);
    __syncthreads();                       // xs/wred reuse guard
    if (tid < WD) {
      xs[tid] = (li < XRCAP) ? XR[(size_t)li * WD + tid]
                             : x[(size_t)n * WD * TD + (size_t)tid * TD + t];
    }
    __syncthreads();

    const float s = np_sumsq64_ptr(xs);    // identical on all threads, np-exact

    unsigned long long best = ~0ull;
#pragma unroll
    for (int p = 0; p < 2; ++p) {
      const int c0 = tid * 8 + p * 4;
      const float4* k0 = (const float4*)(k + (size_t)c0 * WD);
      const float4* k1 = (const float4*)(k + (size_t)(c0 + 1) * WD);
      const float4* k2 = (const float4*)(k + (size_t)(c0 + 2) * WD);
      const float4* k3 = (const float4*)(k + (size_t)(c0 + 3) * WD);
      float g0 = 0.f, g1 = 0.f, g2 = 0.f, g3 = 0.f;
#pragma unroll
      for (int q = 0; q < 16; ++q) {
        float4 a = k0[q], b = k1[q], c = k2[q], d = k3[q];
        float q0 = xs[4 * q], q1 = xs[4 * q + 1];
        float q2 = xs[4 * q + 2], q3 = xs[4 * q + 3];
        g0 = __fmaf_rn(q0, a.x, g0); g0 = __fmaf_rn(q1, a.y, g0);
        g0 = __fmaf_rn(q2, a.z, g0); g0 = __fmaf_rn(q3, a.w, g0);
        g1 = __fmaf_rn(q0, b.x, g1); g1 = __fmaf_rn(q1, b.y, g1);
        g1 = __fmaf_rn(q2, b.z, g1); g1 = __fmaf_rn(q3, b.w, g1);
        g2 = __fmaf_rn(q0, c.x, g2); g2 = __fmaf_rn(q1, c.y, g2);
        g2 = __fmaf_rn(q2, c.z, g2); g2 = __fmaf_rn(q3, c.w, g2);
        g3 = __fmaf_rn(q0, d.x, g3); g3 = __fmaf_rn(q1, d.y, g3);
        g3 = __fmaf_rn(q2, d.z, g3); g3 = __fmaf_rn(q3, d.w, g3);
      }
      float d0 = __fadd_rn(__fsub_rn(s, __fmul_rn(2.f, g0)), kn2[c0]);
      float d1 = __fadd_rn(__fsub_rn(s, __fmul_rn(2.f, g1)), kn2[c0 + 1]);
      float d2 = __fadd_rn(__fsub_rn(s, __fmul_rn(2.f, g2)), kn2[c0 + 2]);
      float d3 = __fadd_rn(__fsub_rn(s, __fmul_rn(2.f, g3)), kn2[c0 + 3]);
      unsigned long long p0 = ((unsigned long long)__float_as_uint(d0) << 32) | (unsigned)(c0);
      unsigned long long p1 = ((unsigned long long)__float_as_uint(d1) << 32) | (unsigned)(c0 + 1);
      unsigned long long p2 = ((unsigned long long)__float_as_uint(d2) << 32) | (unsigned)(c0 + 2);
      unsigned long long p3 = ((unsigned long long)__float_as_uint(d3) << 32) | (unsigned)(c0 + 3);
      best = p0 < best ? p0 : best;
      best = p1 < best ? p1 : best;
      best = p2 < best ? p2 : best;
      best = p3 < best ? p3 : best;
    }
    // wave reduce (u64 via hi/lo shfl), then block reduce via LDS
#pragma unroll
    for (int d = 1; d < 64; d <<= 1) {
      unsigned lo = (unsigned)best, hi = (unsigned)(best >> 32);
      unsigned olo = __shfl_xor(lo, d, 64);
      unsigned ohi = __shfl_xor(hi, d, 64);
      unsigned long long o = ((unsigned long long)ohi << 32) | olo;
      best = o < best ? o : best;
    }
    if (lane == 0) wred[wv] = best;
    __syncthreads();
    if (tid == 0) {
      unsigned long long b = wred[0];
      b = wred[1] < b ? wred[1] : b;
      b = wred[2] < b ? wred[2] : b;
      b = wred[3] < b ? wred[3] : b;
      bbest = b;
    }
    __syncthreads();
    const unsigned long long fb = bbest;
    const int bi = (int)(fb & 0xffffffffu);
    const float bv = __uint_as_float((unsigned)(fb >> 32));
    if (tid < WD) {                        // first wave exactly: epilogue
      float kw = k[(size_t)bi * WD + tid];
      float xw = xs[tid];
      float diff = __fsub_rn(kw, xw);
      out[OFF_XD + (size_t)n * WD * TD + (size_t)tid * TD + t] = __fadd_rn(xw, diff);
      double d2 = (double)diff * (double)diff;
#pragma unroll
      for (int dd = 32; dd > 0; dd >>= 1) d2 += __shfl_down(d2, dd, 64);
      if (tid == 0) {
        out[OFF_XL + row] = (float)bi;
        atomicAdd(&red[2], (double)bv);
        atomicAdd(&red[3], d2);
      }
    }
  }
}

__global__ void vq_final(const char* __restrict__ wsb, float* __restrict__ out) {
  const double* red = (const double*)(wsb + RED_OFF);
  double sum = red[0], sumsq = red[1];
  double mean = sum / 8388608.0;
  double ss = sumsq - sum * mean;
  if (ss < 0.0) ss = 0.0;
  out[OFF_SC + 0] = (float)(red[3] / 8388608.0);       // commit_loss
  out[OFF_SC + 1] = (float)(red[2] / 131072.0);        // fit
  out[OFF_SC + 2] = (float)sqrt(ss / 8388608.0);       // prenorm
}

extern "C" void kernel_launch(void* const* d_in, const int* in_sizes, int n_in,
                              void* d_out, int out_size, void* d_ws, size_t ws_size,
                              hipStream_t stream) {
  const float* x = (const float*)d_in[0];
  const float* k = (const float*)d_in[1];
  float* out = (float*)d_out;
  char* wsb = (char*)d_ws;

  hipMemsetAsync(d_ws, 0, 64, stream);                 // red[4] + count
  vq_prep<<<KB / 256, 256, 0, stream>>>(k, wsb);
  vq_scan<<<NT / 128, 256, 0, stream>>>(x, wsb);
  vq_fin<<<NT / 256, 256, 0, stream>>>(x, k, out, wsb);
  vq_rescan4<<<4096, 256, 0, stream>>>(x, k, out, wsb);
  vq_final<<<1, 1, 0, stream>>>(wsb, out);
}

// Round 11
// 357.005 us; speedup vs baseline: 3.0475x; 1.9560x over previous
//
#include <hip/hip_runtime.h>
#include <math.h>

#define WD 64
#define TD 8192
#define NT 131072           // 16 * 8192 rows
#define KB 2048
// Output layout (float32, concatenated): x_l [NT], x_d [NT*WD], commit, fit, prenorm
#define OFF_XL 0
#define OFF_XD NT
#define OFF_SC (NT + NT * WD)

// ws layout (bytes)
#define RED_OFF   0                      // double[4]: xsum, xsumsq, fit, commit
#define CNT_OFF   32                     // uint: rescan count
#define KN2_OFF   4096                   // float[2048] np-exact ||k||^2
#define CB_OFF    16384                  // bf16 B-frags: 128jt * 4frag * 64lane * 16B = 512KB
#define M1_OFF    (16384 + 524288)       // float[NT]
#define M2_OFF    (M1_OFF + 4 * NT)      // float[NT]
#define J1_OFF    (M2_OFF + 4 * NT)      // int[NT]
#define LIST_OFF  (J1_OFF + 4 * NT)      // int[NT] rescan rows
#define KT_OFF    (LIST_OFF + 4 * NT)    // float[64][2048] transposed codebook (512KB, reuses old P1 slot)
#define XR_OFF    (KT_OFF + 8 * NT)      // float[XRCAP][64] compacted rescan rows
#define XRCAP     32768                  // 8MB cap (count ~2.7k observed r5-r10)

#define EPS_GAP 4e-3f    // approx top-2 gap below this -> exact rescan (~2% rows)
#define VEPS    2e-3f    // |approx score(j1) - exact score(j1)| above this -> rescan (~0)

typedef __attribute__((ext_vector_type(8))) short bf16x8_t;  // 8 bf16 (4 VGPRs)
typedef __attribute__((ext_vector_type(4))) float f32x4_t;

__device__ __forceinline__ unsigned short bf16_rne(float f) {
  unsigned int u = __float_as_uint(f);
  unsigned int r = u + 0x7fffu + ((u >> 16) & 1u);
  return (unsigned short)(r >> 16);
}

#define REP64(F) F(0) F(1) F(2) F(3) F(4) F(5) F(6) F(7) \
  F(8) F(9) F(10) F(11) F(12) F(13) F(14) F(15) \
  F(16) F(17) F(18) F(19) F(20) F(21) F(22) F(23) \
  F(24) F(25) F(26) F(27) F(28) F(29) F(30) F(31) \
  F(32) F(33) F(34) F(35) F(36) F(37) F(38) F(39) \
  F(40) F(41) F(42) F(43) F(44) F(45) F(46) F(47) \
  F(48) F(49) F(50) F(51) F(52) F(53) F(54) F(55) \
  F(56) F(57) F(58) F(59) F(60) F(61) F(62) F(63)

// numpy pairwise_sum (scalar 8-accumulator, n=64) of PRE-ROUNDED squares; *_rn
// intrinsics forbid contraction. Bit-exact vs np.sum(a*a, -1) (verified r2-r10).
#define NP_SUMSQ64_NAMED(SVAR) \
  float r0 = __fmul_rn(x0, x0); \
  float r1 = __fmul_rn(x1, x1); \
  float r2 = __fmul_rn(x2, x2); \
  float r3 = __fmul_rn(x3, x3); \
  float r4 = __fmul_rn(x4, x4); \
  float r5 = __fmul_rn(x5, x5); \
  float r6 = __fmul_rn(x6, x6); \
  float r7 = __fmul_rn(x7, x7); \
  SQ8(8, 9, 10, 11, 12, 13, 14, 15) \
  SQ8(16, 17, 18, 19, 20, 21, 22, 23) \
  SQ8(24, 25, 26, 27, 28, 29, 30, 31) \
  SQ8(32, 33, 34, 35, 36, 37, 38, 39) \
  SQ8(40, 41, 42, 43, 44, 45, 46, 47) \
  SQ8(48, 49, 50, 51, 52, 53, 54, 55) \
  SQ8(56, 57, 58, 59, 60, 61, 62, 63) \
  const float SVAR = __fadd_rn(__fadd_rn(__fadd_rn(r0, r1), __fadd_rn(r2, r3)), \
                               __fadd_rn(__fadd_rn(r4, r5), __fadd_rn(r6, r7)));
#define SQ8(a,b,c,d,e,f,g,h) \
  r0 = __fadd_rn(r0, __fmul_rn(x##a, x##a)); \
  r1 = __fadd_rn(r1, __fmul_rn(x##b, x##b)); \
  r2 = __fadd_rn(r2, __fmul_rn(x##c, x##c)); \
  r3 = __fadd_rn(r3, __fmul_rn(x##d, x##d)); \
  r4 = __fadd_rn(r4, __fmul_rn(x##e, x##e)); \
  r5 = __fadd_rn(r5, __fmul_rn(x##f, x##f)); \
  r6 = __fadd_rn(r6, __fmul_rn(x##g, x##g)); \
  r7 = __fadd_rn(r7, __fmul_rn(x##h, x##h));

__device__ __forceinline__ float np_sumsq64_ptr(const float* a) {
  float r0 = __fmul_rn(a[0], a[0]);
  float r1 = __fmul_rn(a[1], a[1]);
  float r2 = __fmul_rn(a[2], a[2]);
  float r3 = __fmul_rn(a[3], a[3]);
  float r4 = __fmul_rn(a[4], a[4]);
  float r5 = __fmul_rn(a[5], a[5]);
  float r6 = __fmul_rn(a[6], a[6]);
  float r7 = __fmul_rn(a[7], a[7]);
#pragma unroll
  for (int i = 8; i < 64; i += 8) {
    r0 = __fadd_rn(r0, __fmul_rn(a[i + 0], a[i + 0]));
    r1 = __fadd_rn(r1, __fmul_rn(a[i + 1], a[i + 1]));
    r2 = __fadd_rn(r2, __fmul_rn(a[i + 2], a[i + 2]));
    r3 = __fadd_rn(r3, __fmul_rn(a[i + 3], a[i + 3]));
    r4 = __fadd_rn(r4, __fmul_rn(a[i + 4], a[i + 4]));
    r5 = __fadd_rn(r5, __fmul_rn(a[i + 5], a[i + 5]));
    r6 = __fadd_rn(r6, __fmul_rn(a[i + 6], a[i + 6]));
    r7 = __fadd_rn(r7, __fmul_rn(a[i + 7], a[i + 7]));
  }
  float t01 = __fadd_rn(r0, r1);
  float t23 = __fadd_rn(r2, r3);
  float t45 = __fadd_rn(r4, r5);
  float t67 = __fadd_rn(r6, r7);
  return __fadd_rn(__fadd_rn(t01, t23), __fadd_rn(t45, t67));
}

// ---------- K0: kn2_np + bf16 B-frags + transposed codebook kT[w][c] ----------
__global__ __launch_bounds__(256)
void vq_prep(const float* __restrict__ k, char* __restrict__ wsb) {
  int c = blockIdx.x * 256 + threadIdx.x;
  if (c >= KB) return;
  const float* kr = k + (size_t)c * WD;
  ((float*)(wsb + KN2_OFF))[c] = np_sumsq64_ptr(kr);
  float* kt = (float*)(wsb + KT_OFF);
#pragma unroll
  for (int w = 0; w < WD; ++w) kt[(size_t)w * KB + c] = kr[w];
  int jt = c >> 4, col = c & 15;
  unsigned short* cb = (unsigned short*)(wsb + CB_OFF);
#pragma unroll
  for (int w = 0; w < WD; ++w) {
    float f = kr[w];
    unsigned short hb = bf16_rne(f);
    float hf = __uint_as_float((unsigned int)hb << 16);
    unsigned short lb = bf16_rne(f - hf);
    int fH = w >> 5;                       // K-half: frag 0/1 (hi), 2/3 (lo)
    int lane = col | (((w >> 3) & 3) << 4);
    int e = w & 7;
    cb[((size_t)((jt * 4 + fH) * 64 + lane)) * 8 + e] = hb;
    cb[((size_t)((jt * 4 + 2 + fH) * 64 + lane)) * 8 + e] = lb;
  }
}

// ---------- K1: MFMA bf16x3 score scan -> per-row (m1, m2, j1) ----------
__global__ __launch_bounds__(256, 3)
void vq_scan(const float* __restrict__ x, char* __restrict__ wsb) {
  __shared__ float lkn2[KB];
  for (int i = threadIdx.x; i < KB; i += 256)
    lkn2[i] = ((const float*)(wsb + KN2_OFF))[i];
  __syncthreads();

  const int tid = threadIdx.x, lane = tid & 63, wave = tid >> 6;
  const int col = lane & 15, grp = lane >> 4;
  const int n = blockIdx.x >> 6;           // 64 blocks per n (8192/128)
  const int t0 = (blockIdx.x & 63) * 128;
  const float* xb = x + (size_t)n * WD * TD;

  bf16x8_t aH[2][2], aL[2][2];             // [tile][k-step]
#pragma unroll
  for (int T = 0; T < 2; ++T) {
    int trow = t0 + wave * 32 + T * 16 + col;
#pragma unroll
    for (int s = 0; s < 2; ++s) {
#pragma unroll
      for (int e = 0; e < 8; ++e) {
        int w = s * 32 + grp * 8 + e;
        float f = xb[(size_t)w * TD + trow];
        unsigned short hb = bf16_rne(f);
        float hf = __uint_as_float((unsigned int)hb << 16);
        unsigned short lb = bf16_rne(f - hf);
        aH[T][s][e] = (short)hb;
        aL[T][s][e] = (short)lb;
      }
    }
  }

  float m1v[2][4], m2v[2][4];
  int j1v[2][4];
#pragma unroll
  for (int T = 0; T < 2; ++T)
#pragma unroll
    for (int e = 0; e < 4; ++e) {
      m1v[T][e] = INFINITY; m2v[T][e] = INFINITY; j1v[T][e] = 0;
    }

  const bf16x8_t* cb = (const bf16x8_t*)(wsb + CB_OFF);
  const f32x4_t zero4 = {0.f, 0.f, 0.f, 0.f};

  for (int jt = 0; jt < 128; ++jt) {
    const bf16x8_t* bp = cb + (size_t)jt * 256 + lane;
    bf16x8_t bH0 = bp[0], bH1 = bp[64], bL0 = bp[128], bL1 = bp[192];
    float kv = lkn2[jt * 16 + col];
    f32x4_t aA0 = __builtin_amdgcn_mfma_f32_16x16x32_bf16(aH[0][0], bH0, zero4, 0, 0, 0);
    f32x4_t aB0 = __builtin_amdgcn_mfma_f32_16x16x32_bf16(aH[0][1], bH1, zero4, 0, 0, 0);
    f32x4_t aA1 = __builtin_amdgcn_mfma_f32_16x16x32_bf16(aH[1][0], bH0, zero4, 0, 0, 0);
    f32x4_t aB1 = __builtin_amdgcn_mfma_f32_16x16x32_bf16(aH[1][1], bH1, zero4, 0, 0, 0);
    aA0 = __builtin_amdgcn_mfma_f32_16x16x32_bf16(aL[0][0], bH0, aA0, 0, 0, 0);
    aB0 = __builtin_amdgcn_mfma_f32_16x16x32_bf16(aL[0][1], bH1, aB0, 0, 0, 0);
    aA1 = __builtin_amdgcn_mfma_f32_16x16x32_bf16(aL[1][0], bH0, aA1, 0, 0, 0);
    aB1 = __builtin_amdgcn_mfma_f32_16x16x32_bf16(aL[1][1], bH1, aB1, 0, 0, 0);
    aA0 = __builtin_amdgcn_mfma_f32_16x16x32_bf16(aH[0][0], bL0, aA0, 0, 0, 0);
    aB0 = __builtin_amdgcn_mfma_f32_16x16x32_bf16(aH[0][1], bL1, aB0, 0, 0, 0);
    aA1 = __builtin_amdgcn_mfma_f32_16x16x32_bf16(aH[1][0], bL0, aA1, 0, 0, 0);
    aB1 = __builtin_amdgcn_mfma_f32_16x16x32_bf16(aH[1][1], bL1, aB1, 0, 0, 0);

    int cd = jt * 16 + col;
#define UPD(T, E, V) { bool b = (V) < m1v[T][E]; \
      m2v[T][E] = b ? m1v[T][E] : fminf(m2v[T][E], (V)); \
      m1v[T][E] = b ? (V) : m1v[T][E]; \
      j1v[T][E] = b ? cd : j1v[T][E]; }
    {
      float v0 = fmaf(-2.f, aA0[0] + aB0[0], kv);
      float v1 = fmaf(-2.f, aA0[1] + aB0[1], kv);
      float v2 = fmaf(-2.f, aA0[2] + aB0[2], kv);
      float v3 = fmaf(-2.f, aA0[3] + aB0[3], kv);
      UPD(0, 0, v0) UPD(0, 1, v1) UPD(0, 2, v2) UPD(0, 3, v3)
      float u0 = fmaf(-2.f, aA1[0] + aB1[0], kv);
      float u1 = fmaf(-2.f, aA1[1] + aB1[1], kv);
      float u2 = fmaf(-2.f, aA1[2] + aB1[2], kv);
      float u3 = fmaf(-2.f, aA1[3] + aB1[3], kv);
      UPD(1, 0, u0) UPD(1, 1, u1) UPD(1, 2, u2) UPD(1, 3, u3)
    }
#undef UPD
  }

#pragma unroll
  for (int T = 0; T < 2; ++T)
#pragma unroll
    for (int e = 0; e < 4; ++e) {
      float m1 = m1v[T][e], m2 = m2v[T][e];
      int j1 = j1v[T][e];
#pragma unroll
      for (int d = 1; d < 16; d <<= 1) {
        float om1 = __shfl_xor(m1, d, 64);
        float om2 = __shfl_xor(m2, d, 64);
        int oj = __shfl_xor(j1, d, 64);
        bool take = (om1 < m1) || (om1 == m1 && oj < j1);
        float loser = take ? m1 : om1;
        m2 = fminf(fminf(m2, om2), loser);
        m1 = take ? om1 : m1;
        j1 = take ? oj : j1;
      }
      if (col == 0) {
        int row = blockIdx.x * 128 + wave * 32 + T * 16 + grp * 4 + e;
        ((float*)(wsb + M1_OFF))[row] = m1;
        ((float*)(wsb + M2_OFF))[row] = m2;
        ((int*)(wsb + J1_OFF))[row] = j1;
      }
    }
}

// ---------- K2: per-row finalize: verify j1, epilogue, flag + compact rescans ----------
__global__ __launch_bounds__(256, 4)
void vq_fin(const float* __restrict__ x, const float* __restrict__ k,
            float* __restrict__ out, char* __restrict__ wsb) {
  __shared__ double sred[16];
  const int tid = threadIdx.x;
  const int row = blockIdx.x * 256 + tid;
  const int n = row >> 13;
  const int t = row & (TD - 1);

  float m1r = ((const float*)(wsb + M1_OFF))[row];
  float m2r = ((const float*)(wsb + M2_OFF))[row];
  int j1r = ((const int*)(wsb + J1_OFF))[row];

  const float* xr = x + ((size_t)n * WD) * TD + t;
#define LOADX(w) float x##w = xr[(size_t)(w) * TD];
  REP64(LOADX)
#undef LOADX

  NP_SUMSQ64_NAMED(s)

  double xsum = 0.0, xsumsq = 0.0;
#define PRE(w) { double xd = (double)x##w; xsum += xd; xsumsq = fma(xd, xd, xsumsq); }
  REP64(PRE)
#undef PRE

  const float* kbr = k + (size_t)j1r * WD;
  float* xo = out + OFF_XD + ((size_t)n * WD) * TD + t;
  double commit = 0.0;
  float g = 0.f;
#define EPI(w) { \
    float kw = kbr[w]; \
    float diff = __fsub_rn(kw, x##w); \
    commit = fma((double)diff, (double)diff, commit); \
    g = __fmaf_rn(x##w, kw, g); \
    xo[(size_t)(w) * TD] = __fadd_rn(x##w, diff); }
  REP64(EPI)
#undef EPI

  float kn2j = ((const float*)(wsb + KN2_OFF))[j1r];
  float score = kn2j - 2.f * g;
  bool resc = (m2r - m1r < EPS_GAP) || (fabsf(score - m1r) > VEPS);
  float dist1 = __fadd_rn(__fsub_rn(s, __fmul_rn(2.f, g)), kn2j);

  out[OFF_XL + row] = (float)j1r;
  if (resc) {
    unsigned idx = atomicAdd((unsigned*)(wsb + CNT_OFF), 1u);
    ((int*)(wsb + LIST_OFF))[idx] = row;
    if (idx < XRCAP) {                                    // compact row for rescan
      float* xrw = (float*)(wsb + XR_OFF) + (size_t)idx * WD;
#define XWR(w) xrw[w] = x##w;
      REP64(XWR)
#undef XWR
    }
  }

  double v0 = xsum, v1 = xsumsq;
  double v2 = resc ? 0.0 : (double)dist1;
  double v3 = resc ? 0.0 : commit;
#pragma unroll
  for (int off = 32; off > 0; off >>= 1) {
    v0 += __shfl_down(v0, off, 64);
    v1 += __shfl_down(v1, off, 64);
    v2 += __shfl_down(v2, off, 64);
    v3 += __shfl_down(v3, off, 64);
  }
  if ((tid & 63) == 0) {
    int wv = tid >> 6;
    sred[wv * 4 + 0] = v0;
    sred[wv * 4 + 1] = v1;
    sred[wv * 4 + 2] = v2;
    sred[wv * 4 + 3] = v3;
  }
  __syncthreads();
  if (tid == 0) {
    double a0 = 0, a1 = 0, a2 = 0, a3 = 0;
#pragma unroll
    for (int w2 = 0; w2 < 4; ++w2) {
      a0 += sred[w2 * 4 + 0];
      a1 += sred[w2 * 4 + 1];
      a2 += sred[w2 * 4 + 2];
      a3 += sred[w2 * 4 + 3];
    }
    double* red = (double*)(wsb + RED_OFF);
    atomicAdd(&red[0], a0);
    atomicAdd(&red[1], a1);
    atomicAdd(&red[2], a2);
    atomicAdd(&red[3], a3);
  }
}

// ---------- K3: exact rescan via TRANSPOSED codebook, one block per row ----------
// Per step w (lockstep over the block): thread loads kT[w][c0..c0+7] (2 coalesced
// float4; block reads 8KB contiguous), FMAs into 8 named accumulators. Live regs
// per iter ~16 -> structurally spill-proof (r9/r10 lesson: per-thread private
// codebook streams spilled at 256 VGPR). Chain per code stays sequential over w
// (np-exact, bit-identical). Block packed-u64 argmin, first-index on ties.
__global__ __launch_bounds__(256)
void vq_rescan5(const float* __restrict__ x, const float* __restrict__ k,
                float* __restrict__ out, char* __restrict__ wsb) {
  __shared__ float xs[WD];
  __shared__ unsigned long long wred[4];
  __shared__ unsigned long long bbest;
  const unsigned count = *(const unsigned*)(wsb + CNT_OFF);
  const int* list = (const int*)(wsb + LIST_OFF);
  const float* kn2 = (const float*)(wsb + KN2_OFF);
  const float* XR = (const float*)(wsb + XR_OFF);
  const float* kT = (const float*)(wsb + KT_OFF);
  double* red = (double*)(wsb + RED_OFF);
  const int tid = threadIdx.x;
  const int lane = tid & 63, wv = tid >> 6;
  const int c0 = tid * 8;

  for (unsigned li = blockIdx.x; li < count; li += gridDim.x) {
    const int row = list[li];
    const int n = row >> 13, t = row & (TD - 1);
    __syncthreads();                       // xs/wred reuse guard
    if (tid < WD) {
      xs[tid] = (li < XRCAP) ? XR[(size_t)li * WD + tid]
                             : x[(size_t)n * WD * TD + (size_t)tid * TD + t];
    }
    __syncthreads();

    const float s = np_sumsq64_ptr(xs);    // identical on all threads, np-exact

    float g0 = 0.f, g1 = 0.f, g2 = 0.f, g3 = 0.f;
    float g4 = 0.f, g5 = 0.f, g6 = 0.f, g7 = 0.f;
    const float* kt = kT + c0;
#pragma unroll 4
    for (int w = 0; w < WD; ++w) {
      const float xw = xs[w];                            // LDS broadcast
      const float4 ka = *(const float4*)(kt + (size_t)w * KB);
      const float4 kb = *(const float4*)(kt + (size_t)w * KB + 4);
      g0 = __fmaf_rn(xw, ka.x, g0);
      g1 = __fmaf_rn(xw, ka.y, g1);
      g2 = __fmaf_rn(xw, ka.z, g2);
      g3 = __fmaf_rn(xw, ka.w, g3);
      g4 = __fmaf_rn(xw, kb.x, g4);
      g5 = __fmaf_rn(xw, kb.y, g5);
      g6 = __fmaf_rn(xw, kb.z, g6);
      g7 = __fmaf_rn(xw, kb.w, g7);
    }

    unsigned long long best = ~0ull;
#define FIN1(i, GV) { \
      float d = __fadd_rn(__fsub_rn(s, __fmul_rn(2.f, GV)), kn2[c0 + i]); \
      unsigned long long p = ((unsigned long long)__float_as_uint(d) << 32) | (unsigned)(c0 + i); \
      best = p < best ? p : best; }
    FIN1(0, g0) FIN1(1, g1) FIN1(2, g2) FIN1(3, g3)
    FIN1(4, g4) FIN1(5, g5) FIN1(6, g6) FIN1(7, g7)
#undef FIN1

    // wave reduce (u64 via hi/lo shfl), then block reduce via LDS
#pragma unroll
    for (int d = 1; d < 64; d <<= 1) {
      unsigned lo = (unsigned)best, hi = (unsigned)(best >> 32);
      unsigned olo = __shfl_xor(lo, d, 64);
      unsigned ohi = __shfl_xor(hi, d, 64);
      unsigned long long o = ((unsigned long long)ohi << 32) | olo;
      best = o < best ? o : best;
    }
    if (lane == 0) wred[wv] = best;
    __syncthreads();
    if (tid == 0) {
      unsigned long long b = wred[0];
      b = wred[1] < b ? wred[1] : b;
      b = wred[2] < b ? wred[2] : b;
      b = wred[3] < b ? wred[3] : b;
      bbest = b;
    }
    __syncthreads();
    const unsigned long long fb = bbest;
    const int bi = (int)(fb & 0xffffffffu);
    const float bv = __uint_as_float((unsigned)(fb >> 32));
    if (tid < WD) {                        // first wave: epilogue
      float kw = k[(size_t)bi * WD + tid];
      float xw = xs[tid];
      float diff = __fsub_rn(kw, xw);
      out[OFF_XD + (size_t)n * WD * TD + (size_t)tid * TD + t] = __fadd_rn(xw, diff);
      double d2 = (double)diff * (double)diff;
#pragma unroll
      for (int dd = 32; dd > 0; dd >>= 1) d2 += __shfl_down(d2, dd, 64);
      if (tid == 0) {
        out[OFF_XL + row] = (float)bi;
        atomicAdd(&red[2], (double)bv);
        atomicAdd(&red[3], d2);
      }
    }
  }
}

__global__ void vq_final(const char* __restrict__ wsb, float* __restrict__ out) {
  const double* red = (const double*)(wsb + RED_OFF);
  double sum = red[0], sumsq = red[1];
  double mean = sum / 8388608.0;
  double ss = sumsq - sum * mean;
  if (ss < 0.0) ss = 0.0;
  out[OFF_SC + 0] = (float)(red[3] / 8388608.0);       // commit_loss
  out[OFF_SC + 1] = (float)(red[2] / 131072.0);        // fit
  out[OFF_SC + 2] = (float)sqrt(ss / 8388608.0);       // prenorm
}

extern "C" void kernel_launch(void* const* d_in, const int* in_sizes, int n_in,
                              void* d_out, int out_size, void* d_ws, size_t ws_size,
                              hipStream_t stream) {
  const float* x = (const float*)d_in[0];
  const float* k = (const float*)d_in[1];
  float* out = (float*)d_out;
  char* wsb = (char*)d_ws;

  hipMemsetAsync(d_ws, 0, 64, stream);                 // red[4] + count
  vq_prep<<<KB / 256, 256, 0, stream>>>(k, wsb);
  vq_scan<<<NT / 128, 256, 0, stream>>>(x, wsb);
  vq_fin<<<NT / 256, 256, 0, stream>>>(x, k, out, wsb);
  vq_rescan5<<<4096, 256, 0, stream>>>(x, k, out, wsb);
  vq_final<<<1, 1, 0, stream>>>(wsb, out);
}